// Round 5
// baseline (267.432 us; speedup 1.0000x reference)
//
#include <hip/hip_runtime.h>
#include <cstdint>

// ---------------------------------------------------------------------------
// AriaTextMoELayer R5: NO weight-transpose pass. GEMMs stage native-layout
// fp32 weights (reg-staged, fp32->bf16 pack, XOR-swizzled LDS writes) with
// T14 split (issue-early / write-late). A staged via gl16 with pre-swizzled
// source so fragment ds_read_b128 is ~conflict-free. fp32 atomicAdd epilogue.
// rc_k = router + x->bf16 only (isolated for diagnosis).
// ---------------------------------------------------------------------------

#define E_ 8
#define H_ 1024
#define I_ 1024
#define ISH_ 2048
#define NTOK 2048

typedef unsigned short u16;
using bf16x8 = __attribute__((ext_vector_type(8))) __bf16;
using f32x4  = __attribute__((ext_vector_type(4))) float;

__device__ __forceinline__ u16 f2bf(float f) {
  union { float f; unsigned u; } v; v.f = f;
  unsigned r = v.u + 0x7fffu + ((v.u >> 16) & 1u);  // RNE
  return (u16)(r >> 16);
}
__device__ __forceinline__ unsigned pk2(float lo, float hi) {
  return ((unsigned)f2bf(hi) << 16) | (unsigned)f2bf(lo);
}

typedef __attribute__((address_space(1))) const void glb_v;
typedef __attribute__((address_space(3))) void lds_v;
__device__ __forceinline__ void gl16(const void* g, void* l) {
  __builtin_amdgcn_global_load_lds((glb_v*)g, (lds_v*)l, 16, 0, 0);
}

// fragment read from [row][32k] u16 tile with 16B-chunk XOR swizzle
__device__ __forceinline__ bf16x8 rdfrag(const u16* base, int row, int lkg) {
  int off = row * 64 + 16 * (lkg ^ ((row >> 2) & 3));
  return *reinterpret_cast<const bf16x8*>(reinterpret_cast<const char*>(base) + off);
}
__device__ __forceinline__ f32x4 mfma16(bf16x8 a, bf16x8 b, f32x4 c) {
  return __builtin_amdgcn_mfma_f32_16x16x32_bf16(a, b, c, 0, 0, 0);
}

// ---------------- router core: one wave per token ----------------
__device__ __forceinline__ void router_body(const float* __restrict__ x,
                                            const float* __restrict__ wr,
                                            float* __restrict__ scores,
                                            int* __restrict__ cnt,
                                            int* __restrict__ list, int tk) {
  int lane = threadIdx.x & 63;
  const float* xr = x + (size_t)tk * H_;
  float acc[E_];
#pragma unroll
  for (int e = 0; e < E_; ++e) acc[e] = 0.f;
  int h0 = lane * 16;
#pragma unroll 4
  for (int i = 0; i < 16; ++i) {
    float xv = xr[h0 + i];
    const float* w = wr + (size_t)(h0 + i) * E_;
#pragma unroll
    for (int e = 0; e < E_; ++e) acc[e] = fmaf(xv, w[e], acc[e]);
  }
#pragma unroll
  for (int off = 32; off > 0; off >>= 1) {
#pragma unroll
    for (int e = 0; e < E_; ++e) acc[e] += __shfl_xor(acc[e], off, 64);
  }
  if (lane == 0) {
    int e0 = 0; float m0 = acc[0];
#pragma unroll
    for (int e = 1; e < E_; ++e) if (acc[e] > m0) { m0 = acc[e]; e0 = e; }
    int e1 = -1; float m1 = -1e30f;
#pragma unroll
    for (int e = 0; e < E_; ++e) if (e != e0 && acc[e] > m1) { m1 = acc[e]; e1 = e; }
    float s0 = 1.f / (1.f + __expf(m1 - m0));
    scores[tk * 2 + 0] = s0;
    scores[tk * 2 + 1] = 1.f - s0;
    int p0 = atomicAdd(&cnt[e0], 1); list[e0 * NTOK + p0] = tk * 2;
    int p1 = atomicAdd(&cnt[e1], 1); list[e1 * NTOK + p1] = tk * 2 + 1;
  }
}

// ================= FAST PATH =================

// rc: [0,512) router | [512,1024) x->bf16
__global__ __launch_bounds__(256) void rc_k(
    const float* __restrict__ x, const float* __restrict__ wr,
    float* __restrict__ scores, int* __restrict__ cnt, int* __restrict__ list,
    u16* __restrict__ xb) {
  int bid = blockIdx.x, t = threadIdx.x;
  if (bid < 512) {
    router_body(x, wr, scores, cnt, list, bid * 4 + (t >> 6));
    return;
  }
  const float4* srcx = (const float4*)x;
  ushort4* dstx = (ushort4*)xb;
  int base = (bid - 512) * 1024 + t;
#pragma unroll
  for (int it = 0; it < 4; ++it) {
    float4 v = srcx[base + it * 256];
    ushort4 o;
    o.x = f2bf(v.x); o.y = f2bf(v.y); o.z = f2bf(v.z); o.w = f2bf(v.w);
    dstx[base + it * 256] = o;
  }
}

// L1: fused SwiGLU GEMMs with native fp32 B staging.
// bid<256: G3 dense (gw/uw, ldb=2048); else G1 expert (fc1, ldb=2048).
// 128x128 tile, BK=32, A gl16-dbuf (swizzled source), B reg-staged single-buf.
__global__ __launch_bounds__(256, 2) void swiglu2_k(
    const u16* __restrict__ xb, const int* __restrict__ cnt,
    const int* __restrict__ list,
    const float* __restrict__ fc1, const float* __restrict__ gw,
    const float* __restrict__ uw,
    u16* __restrict__ act, u16* __restrict__ tmp) {
  __shared__ __align__(16) u16 As[2][128][32];
  __shared__ __align__(16) u16 B1s[128][32];
  __shared__ __align__(16) u16 B2s[128][32];

  int bid = blockIdx.x;
  int m0, n0, Me, obase = 0, ldo;
  const float *B1, *B2;
  const int* rowmap = nullptr;
  u16* Out;
  if (bid < 256) {  // G3 shared experts
    int mb = bid >> 4, nb = bid & 15;
    m0 = mb * 128; n0 = nb * 128; Me = NTOK;
    B1 = gw + n0; B2 = uw + n0;
    Out = tmp; ldo = ISH_;
  } else {  // G1 expert fc1
    int b2 = bid - 256; int e = b2 >> 7, r = b2 & 127, mb = r >> 3, nb = r & 7;
    Me = cnt[e]; m0 = mb * 128;
    if (m0 >= Me) return;
    n0 = nb * 128;
    rowmap = list + e * NTOK;
    const float* fe = fc1 + ((size_t)e << 21);
    B1 = fe + n0; B2 = fe + 1024 + n0;
    int off = 0;
    for (int q = 0; q < e; ++q) off += cnt[q];
    obase = off; Out = act; ldo = I_;
  }
  const int ldb = 2048;
  int t = threadIdx.x, wid = t >> 6, lane = t & 63;
  int wm = wid & 1, wn = wid >> 1, lr = lane & 15, lkg = lane >> 4;
  int crw = lane >> 2;
  int cqs = (lane & 3) ^ ((lane >> 4) & 3);  // pre-swizzled A source chunk

  const u16* arow[2];
#pragma unroll
  for (int i = 0; i < 2; ++i) {
    int c = wid * 2 + i;
    int rl = m0 + c * 16 + crw;
    int rc = rl < Me ? rl : (Me - 1);
    int tok = rowmap ? (rowmap[rc] >> 1) : rc;
    arow[i] = xb + (size_t)tok * 1024 + cqs * 8;
  }
  int bn4 = (t & 31) * 4;   // n offset
  int bkq = (t >> 5) * 4;   // k row
  int q8 = t >> 5;          // 8B unit index (k/4)
  int wboff[4];
#pragma unroll
  for (int j = 0; j < 4; ++j) {
    int n = bn4 + j;
    wboff[j] = n * 64 + 16 * ((q8 >> 1) ^ ((n >> 2) & 3)) + 8 * (q8 & 1);
  }

  float4 bv1[4], bv2[4];
  auto loadB = [&](int k0) {
    const float* p1 = B1 + (size_t)(k0 + bkq) * ldb + bn4;
    const float* p2 = B2 + (size_t)(k0 + bkq) * ldb + bn4;
#pragma unroll
    for (int i = 0; i < 4; ++i) {
      bv1[i] = *reinterpret_cast<const float4*>(p1 + (size_t)i * ldb);
      bv2[i] = *reinterpret_cast<const float4*>(p2 + (size_t)i * ldb);
    }
  };
  auto writeB = [&]() {
#pragma unroll
    for (int j = 0; j < 4; ++j) {
      unsigned lo1 = pk2(((const float*)&bv1[0])[j], ((const float*)&bv1[1])[j]);
      unsigned hi1 = pk2(((const float*)&bv1[2])[j], ((const float*)&bv1[3])[j]);
      *reinterpret_cast<uint2*>(reinterpret_cast<char*>(&B1s[0][0]) + wboff[j]) =
          make_uint2(lo1, hi1);
      unsigned lo2 = pk2(((const float*)&bv2[0])[j], ((const float*)&bv2[1])[j]);
      unsigned hi2 = pk2(((const float*)&bv2[2])[j], ((const float*)&bv2[3])[j]);
      *reinterpret_cast<uint2*>(reinterpret_cast<char*>(&B2s[0][0]) + wboff[j]) =
          make_uint2(lo2, hi2);
    }
  };
  auto stageA = [&](int cb, int k0) {
#pragma unroll
    for (int i = 0; i < 2; ++i)
      gl16(arow[i] + k0, (u16*)As + cb * 4096 + (wid * 2 + i) * 512);
  };

  f32x4 aP[4][4] = {}, aG[4][4] = {};
  auto compute = [&](int cb) {
    const u16* Ab = (const u16*)As + cb * 4096;
    bf16x8 af[4];
#pragma unroll
    for (int f = 0; f < 4; ++f) af[f] = rdfrag(Ab, wm * 64 + f * 16 + lr, lkg);
#pragma unroll
    for (int fn = 0; fn < 4; ++fn) {
      bf16x8 b1 = rdfrag(&B1s[0][0], wn * 64 + fn * 16 + lr, lkg);
      bf16x8 b2 = rdfrag(&B2s[0][0], wn * 64 + fn * 16 + lr, lkg);
#pragma unroll
      for (int fm = 0; fm < 4; ++fm) {
        aP[fm][fn] = mfma16(af[fm], b1, aP[fm][fn]);
        aG[fm][fn] = mfma16(af[fm], b2, aG[fm][fn]);
      }
    }
  };

  loadB(0);
  stageA(0, 0);
  writeB();
  __syncthreads();
  int cur = 0;
  for (int k0 = 0; k0 < 1024; k0 += 32) {
    bool more = (k0 + 32) < 1024;
    if (more) { stageA(cur ^ 1, k0 + 32); loadB(k0 + 32); }
    compute(cur);
    __syncthreads();
    if (more) writeB();
    __syncthreads();
    cur ^= 1;
  }

#pragma unroll
  for (int fm = 0; fm < 4; ++fm)
#pragma unroll
    for (int fn = 0; fn < 4; ++fn)
#pragma unroll
      for (int j = 0; j < 4; ++j) {
        int row = m0 + wm * 64 + fm * 16 + (lane >> 4) * 4 + j;
        if (row < Me) {
          float p = aP[fm][fn][j], g = aG[fm][fn][j];
          float s = p / (1.f + __expf(-p)) * g;
          Out[(size_t)(obase + row) * ldo + n0 + wn * 64 + fn * 16 + lr] = f2bf(s);
        }
      }
}

// L2': fused fc2 + down GEMMs, native fp32 B staging, atomicAdd epilogue.
// MODE 0 (fc2): BN=128, ldb=1024; v*score -> out[token]. A=act lda=1024.
// MODE 1 (down): BN=64, ldb=1024, split-K2; v -> out[row]. A=tmp lda=2048.
template <int MODE>
__device__ __forceinline__ void out_body2(
    const u16* __restrict__ Ab, int lda, const float* __restrict__ Bb,
    int Me, int m0, int n0, const int* __restrict__ listE,
    const float* __restrict__ scores, float* __restrict__ out, char* smem) {
  constexpr int BNx = MODE ? 64 : 128;
  constexpr int FN = BNx / 32;
  u16* As = (u16*)smem;            // [2][128][32]
  u16* Bs = (u16*)(smem + 16384);  // [BNx][32]
  const int ldb = 1024;

  int t = threadIdx.x, wid = t >> 6, lane = t & 63;
  int wm = wid & 1, wn = wid >> 1, lr = lane & 15, lkg = lane >> 4;
  int crw = lane >> 2;
  int cqs = (lane & 3) ^ ((lane >> 4) & 3);

  const u16* arow[2];
#pragma unroll
  for (int i = 0; i < 2; ++i) {
    int c = wid * 2 + i;
    int rl = m0 + c * 16 + crw;
    int rc = rl < Me ? rl : (Me - 1);
    arow[i] = Ab + (size_t)rc * lda + cqs * 8;
  }

  // B staging mapping
  int bn4, bkq, wboff[4];
  if (MODE == 0) {
    bn4 = (t & 31) * 4; bkq = (t >> 5) * 4;
    int q8 = t >> 5;
#pragma unroll
    for (int j = 0; j < 4; ++j) {
      int n = bn4 + j;
      wboff[j] = n * 64 + 16 * ((q8 >> 1) ^ ((n >> 2) & 3)) + 8 * (q8 & 1);
    }
  } else {
    bn4 = (t & 15) * 4; bkq = (t >> 4) * 2;
    int p = t >> 4;  // k-pair index 0..15
#pragma unroll
    for (int j = 0; j < 4; ++j) {
      int n = bn4 + j;
      wboff[j] = n * 64 + 16 * ((p >> 2) ^ ((n >> 2) & 3)) + 4 * (p & 3);
    }
  }

  float4 bv[4];
  auto loadB = [&](int k0) {
    const float* p = Bb + (size_t)(k0 + bkq) * ldb + bn4;
#pragma unroll
    for (int i = 0; i < (MODE ? 2 : 4); ++i)
      bv[i] = *reinterpret_cast<const float4*>(p + (size_t)i * ldb);
  };
  auto writeB = [&]() {
#pragma unroll
    for (int j = 0; j < 4; ++j) {
      if (MODE == 0) {
        unsigned lo = pk2(((const float*)&bv[0])[j], ((const float*)&bv[1])[j]);
        unsigned hi = pk2(((const float*)&bv[2])[j], ((const float*)&bv[3])[j]);
        *reinterpret_cast<uint2*>(reinterpret_cast<char*>(Bs) + wboff[j]) =
            make_uint2(lo, hi);
      } else {
        unsigned w = pk2(((const float*)&bv[0])[j], ((const float*)&bv[1])[j]);
        *reinterpret_cast<unsigned*>(reinterpret_cast<char*>(Bs) + wboff[j]) = w;
      }
    }
  };
  auto stageA = [&](int cb, int k0) {
#pragma unroll
    for (int i = 0; i < 2; ++i)
      gl16(arow[i] + k0, As + cb * 4096 + (wid * 2 + i) * 512);
  };

  f32x4 acc[4][FN] = {};
  auto compute = [&](int cb) {
    const u16* Ap = As + cb * 4096;
    bf16x8 af[4];
#pragma unroll
    for (int f = 0; f < 4; ++f) af[f] = rdfrag(Ap, wm * 64 + f * 16 + lr, lkg);
#pragma unroll
    for (int fn = 0; fn < FN; ++fn) {
      bf16x8 bb = rdfrag(Bs, wn * (BNx / 2) + fn * 16 + lr, lkg);
#pragma unroll
      for (int fm = 0; fm < 4; ++fm)
        acc[fm][fn] = mfma16(af[fm], bb, acc[fm][fn]);
    }
  };

  loadB(0);
  stageA(0, 0);
  writeB();
  __syncthreads();
  int cur = 0;
  for (int k0 = 0; k0 < 1024; k0 += 32) {
    bool more = (k0 + 32) < 1024;
    if (more) { stageA(cur ^ 1, k0 + 32); loadB(k0 + 32); }
    compute(cur);
    __syncthreads();
    if (more) writeB();
    __syncthreads();
    cur ^= 1;
  }

#pragma unroll
  for (int fm = 0; fm < 4; ++fm)
#pragma unroll
    for (int fn = 0; fn < FN; ++fn)
#pragma unroll
      for (int j = 0; j < 4; ++j) {
        int row = m0 + wm * 64 + fm * 16 + lkg * 4 + j;
        if (row < Me) {
          float v = acc[fm][fn][j];
          int c = n0 + wn * (BNx / 2) + fn * 16 + lr;
          if (MODE == 0) {
            int slot = listE[row];
            atomicAdd(&out[(size_t)(slot >> 1) * H_ + c], v * scores[slot]);
          } else {
            atomicAdd(&out[(size_t)row * H_ + c], v);
          }
        }
      }
}

__global__ __launch_bounds__(256, 2) void out2_k(
    const u16* __restrict__ act, const float* __restrict__ fc2,
    const u16* __restrict__ tmp, const float* __restrict__ dw,
    const int* __restrict__ cnt, const int* __restrict__ list,
    const float* __restrict__ scores, float* __restrict__ out) {
  __shared__ __align__(16) char smem[24576];
  int bid = blockIdx.x;
  if (bid < 1024) {  // fc2: 8 experts x (16 mtiles x 8 ntiles)
    int e = bid >> 7, r = bid & 127, mb = r >> 3, nb = r & 7;
    int Me = cnt[e], m0 = mb * 128;
    if (m0 >= Me) return;
    int off = 0;
    for (int q = 0; q < e; ++q) off += cnt[q];
    out_body2<0>(act + (size_t)off * 1024, 1024,
                 fc2 + ((size_t)e << 20) + (nb * 128),
                 Me, m0, nb * 128, list + e * NTOK, scores, out, smem);
  } else {  // down split-K2: ks x 16 mtiles x 16 ntiles
    int r = bid - 1024, ks = r >> 8, rr = r & 255, mb = rr >> 4, nb = rr & 15;
    out_body2<1>(tmp + ks * 1024, 2048,
                 dw + (size_t)ks * 1024 * 1024 + (nb * 64),
                 NTOK, mb * 128, nb * 64, nullptr, nullptr, out, smem);
  }
}

// ================= FALLBACK PATH (R1, proven) =================
#define BM 128
#define BN 64
#define BK 32
#define PK (BK + 8)

__global__ void router_k(const float* __restrict__ x, const float* __restrict__ wr,
                         float* __restrict__ scores, int* __restrict__ cnt,
                         int* __restrict__ list) {
  int wid = threadIdx.x >> 6;
  int tk = blockIdx.x * 4 + wid;
  if (tk >= NTOK) return;
  router_body(x, wr, scores, cnt, list, tk);
}

__global__ void offs_k(const int* __restrict__ cnt, int* __restrict__ offs) {
  if (threadIdx.x == 0 && blockIdx.x == 0) {
    int s = 0;
    for (int e = 0; e < E_; ++e) { offs[e] = s; s += cnt[e]; }
  }
}

__global__ void cvt_k(const float* __restrict__ x, u16* __restrict__ xb, int n4) {
  int i = blockIdx.x * blockDim.x + threadIdx.x;
  if (i >= n4) return;
  float4 v = reinterpret_cast<const float4*>(x)[i];
  ushort4 o;
  o.x = f2bf(v.x); o.y = f2bf(v.y); o.z = f2bf(v.z); o.w = f2bf(v.w);
  reinterpret_cast<ushort4*>(xb)[i] = o;
}

template <int EXPERT>
__global__ __launch_bounds__(256) void swiglu_gemm_k(
    const u16* __restrict__ A, int lda,
    const int* __restrict__ list, const int* __restrict__ cnt, const int* __restrict__ offs,
    const float* __restrict__ B1g, const float* __restrict__ B2g, int ldb, long long bstride,
    u16* __restrict__ Out, int ldo, int K) {
  __shared__ u16 As[BM][PK];
  __shared__ u16 Bs[2][BN][PK];
  int e = EXPERT ? blockIdx.z : 0;
  int Me = EXPERT ? cnt[e] : NTOK;
  int m0 = blockIdx.y * BM;
  if (m0 >= Me) return;
  int n0 = blockIdx.x * BN;
  const int* rowmap = EXPERT ? (list + e * NTOK) : nullptr;
  const float* B1 = B1g + (EXPERT ? (long long)e * bstride : 0);
  const float* B2 = B2g + (EXPERT ? (long long)e * bstride : 0);
  int t = threadIdx.x, wid = t >> 6, lane = t & 63;
  int wm = wid & 1, wn = wid >> 1, lr = lane & 15, lkg = lane >> 4;
  f32x4 accP[4][2] = {}, accG[4][2] = {};
  for (int k0 = 0; k0 < K; k0 += BK) {
#pragma unroll
    for (int it = 0; it < 2; ++it) {
      int idx = it * 256 + t, r = idx >> 2, q = idx & 3, row = m0 + r;
      uint4 v = make_uint4(0u, 0u, 0u, 0u);
      if (row < Me) {
        int rg = EXPERT ? (rowmap[row] >> 1) : row;
        v = *reinterpret_cast<const uint4*>(A + (size_t)rg * lda + k0 + q * 8);
      }
      *reinterpret_cast<uint4*>(&As[r][q * 8]) = v;
    }
#pragma unroll
    for (int b = 0; b < 2; ++b) {
      const float* Bp = b ? B2 : B1;
#pragma unroll
      for (int it = 0; it < 2; ++it) {
        int idx = (it * 256 + t) * 4, kr = idx >> 6, c = idx & 63;
        float4 f = *reinterpret_cast<const float4*>(Bp + (size_t)(k0 + kr) * ldb + n0 + c);
        Bs[b][c + 0][kr] = f2bf(f.x); Bs[b][c + 1][kr] = f2bf(f.y);
        Bs[b][c + 2][kr] = f2bf(f.z); Bs[b][c + 3][kr] = f2bf(f.w);
      }
    }
    __syncthreads();
    bf16x8 af[4];
#pragma unroll
    for (int fm = 0; fm < 4; ++fm)
      af[fm] = *reinterpret_cast<const bf16x8*>(&As[wm * 64 + fm * 16 + lr][lkg * 8]);
#pragma unroll
    for (int fn = 0; fn < 2; ++fn) {
      bf16x8 bp = *reinterpret_cast<const bf16x8*>(&Bs[0][wn * 32 + fn * 16 + lr][lkg * 8]);
      bf16x8 bg = *reinterpret_cast<const bf16x8*>(&Bs[1][wn * 32 + fn * 16 + lr][lkg * 8]);
#pragma unroll
      for (int fm = 0; fm < 4; ++fm) {
        accP[fm][fn] = __builtin_amdgcn_mfma_f32_16x16x32_bf16(af[fm], bp, accP[fm][fn], 0, 0, 0);
        accG[fm][fn] = __builtin_amdgcn_mfma_f32_16x16x32_bf16(af[fm], bg, accG[fm][fn], 0, 0, 0);
      }
    }
    __syncthreads();
  }
#pragma unroll
  for (int fm = 0; fm < 4; ++fm)
#pragma unroll
    for (int fn = 0; fn < 2; ++fn)
#pragma unroll
      for (int j = 0; j < 4; ++j) {
        int grow = wm * 64 + fm * 16 + lkg * 4 + j, gcol = wn * 32 + fn * 16 + lr;
        int row = m0 + grow;
        if (row < Me) {
          float p = accP[fm][fn][j], g = accG[fm][fn][j];
          float s = p / (1.f + __expf(-p)) * g;
          int orow = EXPERT ? (offs[e] + row) : row;
          Out[(size_t)orow * ldo + n0 + gcol] = f2bf(s);
        }
      }
}

template <int EXPERT>
__global__ __launch_bounds__(256) void out_gemm_k(
    const u16* __restrict__ A, int lda,
    const int* __restrict__ cnt, const int* __restrict__ offs,
    const int* __restrict__ list, const float* __restrict__ scores,
    const float* __restrict__ Bg, int ldb, long long bstride,
    float* __restrict__ Out, const float* __restrict__ outbuf, int K) {
  __shared__ u16 As[BM][PK];
  __shared__ u16 Bs[BN][PK];
  int e = EXPERT ? blockIdx.z : 0;
  int Me = EXPERT ? cnt[e] : NTOK;
  int m0 = blockIdx.y * BM;
  if (m0 >= Me) return;
  int n0 = blockIdx.x * BN;
  const float* B = Bg + (EXPERT ? (long long)e * bstride : 0);
  int aoff = EXPERT ? offs[e] : 0;
  int t = threadIdx.x, wid = t >> 6, lane = t & 63;
  int wm = wid & 1, wn = wid >> 1, lr = lane & 15, lkg = lane >> 4;
  f32x4 acc[4][2] = {};
  for (int k0 = 0; k0 < K; k0 += BK) {
#pragma unroll
    for (int it = 0; it < 2; ++it) {
      int idx = it * 256 + t, r = idx >> 2, q = idx & 3, row = m0 + r;
      uint4 v = make_uint4(0u, 0u, 0u, 0u);
      if (row < Me)
        v = *reinterpret_cast<const uint4*>(A + (size_t)(aoff + row) * lda + k0 + q * 8);
      *reinterpret_cast<uint4*>(&As[r][q * 8]) = v;
    }
#pragma unroll
    for (int it = 0; it < 2; ++it) {
      int idx = (it * 256 + t) * 4, kr = idx >> 6, c = idx & 63;
      float4 f = *reinterpret_cast<const float4*>(B + (size_t)(k0 + kr) * ldb + n0 + c);
      Bs[c + 0][kr] = f2bf(f.x); Bs[c + 1][kr] = f2bf(f.y);
      Bs[c + 2][kr] = f2bf(f.z); Bs[c + 3][kr] = f2bf(f.w);
    }
    __syncthreads();
    bf16x8 af[4];
#pragma unroll
    for (int fm = 0; fm < 4; ++fm)
      af[fm] = *reinterpret_cast<const bf16x8*>(&As[wm * 64 + fm * 16 + lr][lkg * 8]);
#pragma unroll
    for (int fn = 0; fn < 2; ++fn) {
      bf16x8 bb = *reinterpret_cast<const bf16x8*>(&Bs[wn * 32 + fn * 16 + lr][lkg * 8]);
#pragma unroll
      for (int fm = 0; fm < 4; ++fm)
        acc[fm][fn] = __builtin_amdgcn_mfma_f32_16x16x32_bf16(af[fm], bb, acc[fm][fn], 0, 0, 0);
    }
    __syncthreads();
  }
#pragma unroll
  for (int fm = 0; fm < 4; ++fm)
#pragma unroll
    for (int fn = 0; fn < 2; ++fn)
#pragma unroll
      for (int j = 0; j < 4; ++j) {
        int grow = wm * 64 + fm * 16 + lkg * 4 + j, gcol = wn * 32 + fn * 16 + lr;
        int row = m0 + grow;
        if (row < Me) {
          float v = acc[fm][fn][j];
          int c = n0 + gcol;
          if (EXPERT) {
            int slot = list[e * NTOK + row];
            Out[(size_t)slot * H_ + c] = v * scores[slot];
          } else {
            Out[(size_t)row * H_ + c] =
                v + outbuf[(size_t)(2 * row) * H_ + c] + outbuf[(size_t)(2 * row + 1) * H_ + c];
          }
        }
      }
}

// ---------------------------------------------------------------------------
extern "C" void kernel_launch(void* const* d_in, const int* in_sizes, int n_in,
                              void* d_out, int out_size, void* d_ws, size_t ws_size,
                              hipStream_t stream) {
  const float* x   = (const float*)d_in[0];
  const float* wr  = (const float*)d_in[1];
  const float* fc1 = (const float*)d_in[2];
  const float* fc2 = (const float*)d_in[3];
  const float* gw  = (const float*)d_in[4];
  const float* uw  = (const float*)d_in[5];
  const float* dw  = (const float*)d_in[6];
  float* out = (float*)d_out;
  char* ws = (char*)d_ws;

  const size_t NEED_FAST = 131072ull + (20ull << 20);
  if (ws_size >= NEED_FAST) {
    float* scores = (float*)ws;
    int* cnt  = (int*)(ws + 16384);
    int* list = (int*)(ws + 16512);
    u16* xb   = (u16*)(ws + 131072);
    u16* act  = (u16*)(ws + 131072 + (4ll << 20));
    u16* tmp  = (u16*)(ws + 131072 + (12ll << 20));

    hipMemsetAsync(cnt, 0, 128, stream);
    hipMemsetAsync(out, 0, (size_t)NTOK * H_ * sizeof(float), stream);
    rc_k<<<1024, 256, 0, stream>>>(x, wr, scores, cnt, list, xb);
    swiglu2_k<<<1280, 256, 0, stream>>>(xb, cnt, list, fc1, gw, uw, act, tmp);
    out2_k<<<1536, 256, 0, stream>>>(act, fc2, tmp, dw, cnt, list, scores, out);
  } else {
    float* scores = (float*)(ws);
    int*   cnt    = (int*)(ws + (16 << 10));
    int*   offs   = (int*)(ws + (16 << 10) + 128);
    int*   list   = (int*)(ws + (16 << 10) + 256);
    u16*   xb     = (u16*)(ws + (96 << 10));
    u16*   act    = (u16*)(ws + (96 << 10) + (4ll << 20));
    u16*   tmp    = (u16*)(ws + (96 << 10) + (12ll << 20));
    float* outbuf = (float*)(ws + (96 << 10) + (20ll << 20));

    hipMemsetAsync(cnt, 0, E_ * sizeof(int), stream);
    router_k<<<NTOK / 4, 256, 0, stream>>>(x, wr, scores, cnt, list);
    offs_k<<<1, 64, 0, stream>>>(cnt, offs);
    cvt_k<<<(NTOK * H_ / 4 + 255) / 256, 256, 0, stream>>>(x, xb, NTOK * H_ / 4);
    swiglu_gemm_k<1><<<dim3(I_ / BN, NTOK / BM, E_), 256, 0, stream>>>(
        xb, H_, list, cnt, offs, fc1, fc1 + I_, 2 * I_, (long long)H_ * 2 * I_, act, I_, H_);
    out_gemm_k<1><<<dim3(H_ / BN, NTOK / BM, E_), 256, 0, stream>>>(
        act, I_, cnt, offs, list, scores, fc2, H_, (long long)I_ * H_, outbuf, nullptr, I_);
    swiglu_gemm_k<0><<<dim3(ISH_ / BN, NTOK / BM, 1), 256, 0, stream>>>(
        xb, H_, nullptr, nullptr, nullptr, gw, uw, ISH_, 0, tmp, ISH_, H_);
    out_gemm_k<0><<<dim3(H_ / BN, NTOK / BM, 1), 256, 0, stream>>>(
        tmp, ISH_, nullptr, nullptr, nullptr, nullptr, dw, H_, 0, out, outbuf, ISH_);
  }
  (void)in_sizes; (void)n_in; (void)out_size;
}

// Round 6
// 267.242 us; speedup vs baseline: 1.0007x; 1.0007x over previous
//
#include <hip/hip_runtime.h>
#include <cstdint>

// ---------------------------------------------------------------------------
// AriaTextMoELayer R6: transposed weights stored TILE-CONTIGUOUS ([nt][kt]
// [128n][32k] bf16, 8KB tiles) so prep writes are contiguous and GEMM B
// staging is one linear gl16 stream. R4-style dbuf GEMMs (1 barrier/K-step),
// fused fc2+down with fp32 atomicAdd epilogue.
// ---------------------------------------------------------------------------

#define E_ 8
#define H_ 1024
#define I_ 1024
#define ISH_ 2048
#define NTOK 2048

typedef unsigned short u16;
using bf16x8 = __attribute__((ext_vector_type(8))) __bf16;
using f32x4  = __attribute__((ext_vector_type(4))) float;

__device__ __forceinline__ u16 f2bf(float f) {
  union { float f; unsigned u; } v; v.f = f;
  unsigned r = v.u + 0x7fffu + ((v.u >> 16) & 1u);  // RNE
  return (u16)(r >> 16);
}
__device__ __forceinline__ unsigned pk2(float lo, float hi) {
  return ((unsigned)f2bf(hi) << 16) | (unsigned)f2bf(lo);
}

typedef __attribute__((address_space(1))) const void glb_v;
typedef __attribute__((address_space(3))) void lds_v;
__device__ __forceinline__ void gl16(const void* g, void* l) {
  __builtin_amdgcn_global_load_lds((glb_v*)g, (lds_v*)l, 16, 0, 0);
}
__device__ __forceinline__ f32x4 mfma16(bf16x8 a, bf16x8 b, f32x4 c) {
  return __builtin_amdgcn_mfma_f32_16x16x32_bf16(a, b, c, 0, 0, 0);
}

// ---------------- router core ----------------
__device__ __forceinline__ void router_body(const float* __restrict__ x,
                                            const float* __restrict__ wr,
                                            float* __restrict__ scores,
                                            int* __restrict__ cnt,
                                            int* __restrict__ list, int tk) {
  int lane = threadIdx.x & 63;
  const float* xr = x + (size_t)tk * H_;
  float acc[E_];
#pragma unroll
  for (int e = 0; e < E_; ++e) acc[e] = 0.f;
  int h0 = lane * 16;
#pragma unroll 4
  for (int i = 0; i < 16; ++i) {
    float xv = xr[h0 + i];
    const float* w = wr + (size_t)(h0 + i) * E_;
#pragma unroll
    for (int e = 0; e < E_; ++e) acc[e] = fmaf(xv, w[e], acc[e]);
  }
#pragma unroll
  for (int off = 32; off > 0; off >>= 1) {
#pragma unroll
    for (int e = 0; e < E_; ++e) acc[e] += __shfl_xor(acc[e], off, 64);
  }
  if (lane == 0) {
    int e0 = 0; float m0 = acc[0];
#pragma unroll
    for (int e = 1; e < E_; ++e) if (acc[e] > m0) { m0 = acc[e]; e0 = e; }
    int e1 = -1; float m1 = -1e30f;
#pragma unroll
    for (int e = 0; e < E_; ++e) if (e != e0 && acc[e] > m1) { m1 = acc[e]; e1 = e; }
    float s0 = 1.f / (1.f + __expf(m1 - m0));
    scores[tk * 2 + 0] = s0;
    scores[tk * 2 + 1] = 1.f - s0;
    int p0 = atomicAdd(&cnt[e0], 1); list[e0 * NTOK + p0] = tk * 2;
    int p1 = atomicAdd(&cnt[e1], 1); list[e1 * NTOK + p1] = tk * 2 + 1;
  }
}

// ---------------- transpose-convert to TILED layout -------------------------
// src fp32 [K][N] -> dst bf16 tiles [nt][kt][128][32], tile = 8KB contiguous.
// Block handles k-span kb*64..+63, n-span nb*128..+127 (= 2 k-tiles).
__device__ __forceinline__ void wtrans2(const float* __restrict__ src,
                                        u16* __restrict__ dst, int K, int N,
                                        int kb, int nb, void* smem) {
  unsigned* lt = (unsigned*)smem;  // [128 n][32 u32 = 64 k]
  int t = threadIdx.x;
  int c = t & 31, k8 = t >> 5;  // c: 32 col-groups of 4; k8: 8 groups of 8 k
  int k0 = kb * 64, n0 = nb * 128;
  const float* sp = src + (size_t)(k0 + k8 * 8) * N + n0 + (c << 2);
  float v[8][4];
#pragma unroll
  for (int j2 = 0; j2 < 8; ++j2) {
    float4 f = *(const float4*)(sp + (size_t)j2 * N);
    v[j2][0] = f.x; v[j2][1] = f.y; v[j2][2] = f.z; v[j2][3] = f.w;
  }
#pragma unroll
  for (int j = 0; j < 4; ++j) {
    int nl = (c << 2) + j;
    uint4 o = make_uint4(pk2(v[0][j], v[1][j]), pk2(v[2][j], v[3][j]),
                         pk2(v[4][j], v[5][j]), pk2(v[6][j], v[7][j]));
    *(uint4*)&lt[nl * 32 + ((k8 ^ (c & 7)) << 2)] = o;
  }
  __syncthreads();
  int ktiles = K >> 5;
  u16* tb = dst + (size_t)(nb * ktiles + kb * 2) * 4096;
#pragma unroll
  for (int it = 0; it < 4; ++it) {
    int lin = it * 256 + t;
    int nl = lin >> 3, kq = lin & 7;
    uint4 o = *(const uint4*)&lt[nl * 32 + ((kq ^ ((nl >> 2) & 7)) << 2)];
    // o = 8 k-values (kq*8..+7) of row nl -> tile s=kq>>2, chunk kq&3
    *(uint4*)(tb + (kq >> 2) * 4096 + nl * 32 + (kq & 3) * 8) = o;
  }
}

// ================= FAST PATH =================

// prep2: [0,512) router | [512,1024) x->bf16 | [1024,3072) fc1 |
// [3072,3328) gw | [3328,3584) uw | [3584,4608) fc2 | [4608,4864) dw
__global__ __launch_bounds__(256) void prep2_k(
    const float* __restrict__ x, const float* __restrict__ wr,
    float* __restrict__ scores, int* __restrict__ cnt, int* __restrict__ list,
    u16* __restrict__ xb,
    const float* __restrict__ fc1, const float* __restrict__ fc2,
    const float* __restrict__ gw, const float* __restrict__ uw,
    const float* __restrict__ dw,
    u16* __restrict__ fc1T, u16* __restrict__ fc2T, u16* __restrict__ gwT,
    u16* __restrict__ uwT, u16* __restrict__ dwT) {
  __shared__ __align__(16) char psm[16384];
  int bid = blockIdx.x, t = threadIdx.x;
  if (bid < 512) {
    router_body(x, wr, scores, cnt, list, bid * 4 + (t >> 6));
    return;
  }
  if (bid < 1024) {
    const float4* srcx = (const float4*)x;
    ushort4* dstx = (ushort4*)xb;
    int base = (bid - 512) * 1024 + t;
#pragma unroll
    for (int it = 0; it < 4; ++it) {
      float4 v = srcx[base + it * 256];
      ushort4 o;
      o.x = f2bf(v.x); o.y = f2bf(v.y); o.z = f2bf(v.z); o.w = f2bf(v.w);
      dstx[base + it * 256] = o;
    }
    return;
  }
  if (bid < 3072) {        // fc1: 8 x [1024][2048]: kb 0..15, nb 0..15
    int b = bid - 1024;
    int e = b >> 8, q = b & 255;
    wtrans2(fc1 + ((size_t)e << 21), fc1T + ((size_t)e << 21), 1024, 2048,
            q & 15, q >> 4, psm);
  } else if (bid < 3328) { // gw [1024][2048]
    int q = bid - 3072;
    wtrans2(gw, gwT, 1024, 2048, q & 15, q >> 4, psm);
  } else if (bid < 3584) { // uw [1024][2048]
    int q = bid - 3328;
    wtrans2(uw, uwT, 1024, 2048, q & 15, q >> 4, psm);
  } else if (bid < 4608) { // fc2: 8 x [1024][1024]: kb 0..15, nb 0..7
    int b = bid - 3584;
    int e = b >> 7, q = b & 127;
    wtrans2(fc2 + ((size_t)e << 20), fc2T + ((size_t)e << 20), 1024, 1024,
            q & 15, q >> 4, psm);
  } else {                 // dw [2048][1024]: kb 0..31, nb 0..7
    int q = bid - 4608;
    wtrans2(dw, dwT, 2048, 1024, q & 31, q >> 5, psm);
  }
}

// L1: fused SwiGLU GEMMs, dbuf, tiled-B linear staging.
// bid<256: G3 dense (gwT/uwT); else G1 expert (fc1T). 128x128, BK=32.
__global__ __launch_bounds__(256, 2) void swiglu3_k(
    const u16* __restrict__ xb, const int* __restrict__ cnt,
    const int* __restrict__ list, const u16* __restrict__ fc1T,
    const u16* __restrict__ gwT, const u16* __restrict__ uwT,
    u16* __restrict__ act, u16* __restrict__ tmp) {
  __shared__ __align__(16) u16 As[2][4096];
  __shared__ __align__(16) u16 B1s[2][4096];
  __shared__ __align__(16) u16 B2s[2][4096];

  int bid = blockIdx.x;
  int m0, n0, Me, obase = 0, ldo;
  const u16 *B1, *B2;  // tile-sequence base; k-tile kt at +kt*4096
  const int* rowmap = nullptr;
  u16* Out;
  if (bid < 256) {  // G3 shared experts: gw/uw [1024][2048] -> nt=nb, 32 kt
    int mb = bid >> 4, nb = bid & 15;
    m0 = mb * 128; n0 = nb * 128; Me = NTOK;
    B1 = gwT + (size_t)(nb * 32) * 4096;
    B2 = uwT + (size_t)(nb * 32) * 4096;
    Out = tmp; ldo = ISH_;
  } else {  // G1 expert fc1: proj nt=nb, gate nt=8+nb
    int b2 = bid - 256; int e = b2 >> 7, r = b2 & 127, mb = r >> 3, nb = r & 7;
    Me = cnt[e]; m0 = mb * 128;
    if (m0 >= Me) return;
    n0 = nb * 128;
    rowmap = list + e * NTOK;
    const u16* fe = fc1T + ((size_t)e << 21);
    B1 = fe + (size_t)(nb * 32) * 4096;
    B2 = fe + (size_t)((8 + nb) * 32) * 4096;
    int off = 0;
    for (int q = 0; q < e; ++q) off += cnt[q];
    obase = off; Out = act; ldo = I_;
  }
  int t = threadIdx.x, wid = t >> 6, lane = t & 63;
  int wm = wid & 1, wn = wid >> 1, lr = lane & 15, lkg = lane >> 4;
  int cq = lane & 3, crw = lane >> 2;

  const u16* arow[2];
#pragma unroll
  for (int i = 0; i < 2; ++i) {
    int c = wid * 2 + i;
    int rl = m0 + c * 16 + crw;
    int rc = rl < Me ? rl : (Me - 1);
    int tok = rowmap ? (rowmap[rc] >> 1) : rc;
    arow[i] = xb + (size_t)tok * 1024 + cq * 8;
  }

  auto stage = [&](int cb, int kt) {
#pragma unroll
    for (int i = 0; i < 2; ++i) {
      int c = wid * 2 + i;
      int bo = wid * 1024 + i * 512;
      gl16(arow[i] + kt * 32, As[cb] + c * 512);
      gl16(B1 + kt * 4096 + bo + lane * 8, B1s[cb] + bo);
      gl16(B2 + kt * 4096 + bo + lane * 8, B2s[cb] + bo);
    }
  };

  f32x4 aP[4][4] = {}, aG[4][4] = {};
  auto compute = [&](int cb) {
    bf16x8 af[4];
#pragma unroll
    for (int f = 0; f < 4; ++f)
      af[f] = *(const bf16x8*)(As[cb] + (wm * 64 + f * 16 + lr) * 32 + lkg * 8);
#pragma unroll
    for (int fn = 0; fn < 4; ++fn) {
      bf16x8 b1 = *(const bf16x8*)(B1s[cb] + (wn * 64 + fn * 16 + lr) * 32 + lkg * 8);
      bf16x8 b2 = *(const bf16x8*)(B2s[cb] + (wn * 64 + fn * 16 + lr) * 32 + lkg * 8);
#pragma unroll
      for (int fm = 0; fm < 4; ++fm) {
        aP[fm][fn] = mfma16(af[fm], b1, aP[fm][fn]);
        aG[fm][fn] = mfma16(af[fm], b2, aG[fm][fn]);
      }
    }
  };

  stage(0, 0);
  __syncthreads();
  int cur = 0;
  for (int kt = 1; kt < 32; ++kt) {
    stage(cur ^ 1, kt);
    compute(cur);
    __syncthreads();
    cur ^= 1;
  }
  compute(cur);

#pragma unroll
  for (int fm = 0; fm < 4; ++fm)
#pragma unroll
    for (int fn = 0; fn < 4; ++fn)
#pragma unroll
      for (int j = 0; j < 4; ++j) {
        int row = m0 + wm * 64 + fm * 16 + lkg * 4 + j;
        if (row < Me) {
          float p = aP[fm][fn][j], g = aG[fm][fn][j];
          float s = p / (1.f + __expf(-p)) * g;
          Out[(size_t)(obase + row) * ldo + n0 + wn * 64 + fn * 16 + lr] = f2bf(s);
        }
      }
}

// L2: fused fc2 + down GEMMs (both BN=128), dbuf, atomicAdd fp32 epilogue.
// bid<1024: fc2 expert e -> out[token] += v*score. else: down split-K2.
__global__ __launch_bounds__(256, 2) void out3_k(
    const u16* __restrict__ act, const u16* __restrict__ fc2T,
    const u16* __restrict__ tmp, const u16* __restrict__ dwT,
    const int* __restrict__ cnt, const int* __restrict__ list,
    const float* __restrict__ scores, float* __restrict__ out) {
  __shared__ __align__(16) u16 As[2][4096];
  __shared__ __align__(16) u16 Bs[2][4096];

  int bid = blockIdx.x;
  int Me, m0, n0, lda, akoff = 0, mode, e = 0;
  const u16 *Ab, *Bt;
  const int* listE = nullptr;
  if (bid < 1024) {  // fc2: [1024][1024] tiled: nt=nb(8), 32 kt
    e = bid >> 7; int r = bid & 127, mb = r >> 3, nb = r & 7;
    Me = cnt[e]; m0 = mb * 128;
    if (m0 >= Me) return;
    n0 = nb * 128;
    int off = 0;
    for (int q = 0; q < e; ++q) off += cnt[q];
    Ab = act + (size_t)off * 1024; lda = 1024;
    Bt = fc2T + ((size_t)e << 20) + (size_t)(nb * 32) * 4096;
    listE = list + e * NTOK; mode = 0;
  } else {  // down: dw [2048][1024] tiled: nt=nb(8), 64 kt; ks picks 32
    int r = bid - 1024, ks = r >> 7, rr = r & 127, mb = rr >> 3, nb = rr & 7;
    Me = NTOK; m0 = mb * 128; n0 = nb * 128;
    Ab = tmp; lda = 2048; akoff = ks * 1024;
    Bt = dwT + (size_t)(nb * 64 + ks * 32) * 4096;
    mode = 1;
  }
  int t = threadIdx.x, wid = t >> 6, lane = t & 63;
  int wm = wid & 1, wn = wid >> 1, lr = lane & 15, lkg = lane >> 4;
  int cq = lane & 3, crw = lane >> 2;

  const u16* arow[2];
#pragma unroll
  for (int i = 0; i < 2; ++i) {
    int c = wid * 2 + i;
    int rl = m0 + c * 16 + crw;
    int rc = rl < Me ? rl : (Me - 1);
    arow[i] = Ab + (size_t)rc * lda + akoff + cq * 8;
  }

  auto stage = [&](int cb, int kt) {
#pragma unroll
    for (int i = 0; i < 2; ++i) {
      int c = wid * 2 + i;
      int bo = wid * 1024 + i * 512;
      gl16(arow[i] + kt * 32, As[cb] + c * 512);
      gl16(Bt + kt * 4096 + bo + lane * 8, Bs[cb] + bo);
    }
  };

  f32x4 acc[4][4] = {};
  auto compute = [&](int cb) {
    bf16x8 af[4];
#pragma unroll
    for (int f = 0; f < 4; ++f)
      af[f] = *(const bf16x8*)(As[cb] + (wm * 64 + f * 16 + lr) * 32 + lkg * 8);
#pragma unroll
    for (int fn = 0; fn < 4; ++fn) {
      bf16x8 bb = *(const bf16x8*)(Bs[cb] + (wn * 64 + fn * 16 + lr) * 32 + lkg * 8);
#pragma unroll
      for (int fm = 0; fm < 4; ++fm)
        acc[fm][fn] = mfma16(af[fm], bb, acc[fm][fn]);
    }
  };

  stage(0, 0);
  __syncthreads();
  int cur = 0;
  for (int kt = 1; kt < 32; ++kt) {
    stage(cur ^ 1, kt);
    compute(cur);
    __syncthreads();
    cur ^= 1;
  }
  compute(cur);

#pragma unroll
  for (int fm = 0; fm < 4; ++fm)
#pragma unroll
    for (int fn = 0; fn < 4; ++fn)
#pragma unroll
      for (int j = 0; j < 4; ++j) {
        int row = m0 + wm * 64 + fm * 16 + lkg * 4 + j;
        if (row < Me) {
          float v = acc[fm][fn][j];
          int c = n0 + wn * 64 + fn * 16 + lr;
          if (mode == 0) {
            int slot = listE[row];
            atomicAdd(&out[(size_t)(slot >> 1) * H_ + c], v * scores[slot]);
          } else {
            atomicAdd(&out[(size_t)row * H_ + c], v);
          }
        }
      }
}

// ================= FALLBACK PATH (R1, proven) =================
#define BM 128
#define BN 64
#define BK 32
#define PK (BK + 8)

__global__ void router_k(const float* __restrict__ x, const float* __restrict__ wr,
                         float* __restrict__ scores, int* __restrict__ cnt,
                         int* __restrict__ list) {
  int wid = threadIdx.x >> 6;
  int tk = blockIdx.x * 4 + wid;
  if (tk >= NTOK) return;
  router_body(x, wr, scores, cnt, list, tk);
}

__global__ void offs_k(const int* __restrict__ cnt, int* __restrict__ offs) {
  if (threadIdx.x == 0 && blockIdx.x == 0) {
    int s = 0;
    for (int e = 0; e < E_; ++e) { offs[e] = s; s += cnt[e]; }
  }
}

__global__ void cvt_k(const float* __restrict__ x, u16* __restrict__ xb, int n4) {
  int i = blockIdx.x * blockDim.x + threadIdx.x;
  if (i >= n4) return;
  float4 v = reinterpret_cast<const float4*>(x)[i];
  ushort4 o;
  o.x = f2bf(v.x); o.y = f2bf(v.y); o.z = f2bf(v.z); o.w = f2bf(v.w);
  reinterpret_cast<ushort4*>(xb)[i] = o;
}

template <int EXPERT>
__global__ __launch_bounds__(256) void swiglu_gemm_k(
    const u16* __restrict__ A, int lda,
    const int* __restrict__ list, const int* __restrict__ cnt, const int* __restrict__ offs,
    const float* __restrict__ B1g, const float* __restrict__ B2g, int ldb, long long bstride,
    u16* __restrict__ Out, int ldo, int K) {
  __shared__ u16 As[BM][PK];
  __shared__ u16 Bs[2][BN][PK];
  int e = EXPERT ? blockIdx.z : 0;
  int Me = EXPERT ? cnt[e] : NTOK;
  int m0 = blockIdx.y * BM;
  if (m0 >= Me) return;
  int n0 = blockIdx.x * BN;
  const int* rowmap = EXPERT ? (list + e * NTOK) : nullptr;
  const float* B1 = B1g + (EXPERT ? (long long)e * bstride : 0);
  const float* B2 = B2g + (EXPERT ? (long long)e * bstride : 0);
  int t = threadIdx.x, wid = t >> 6, lane = t & 63;
  int wm = wid & 1, wn = wid >> 1, lr = lane & 15, lkg = lane >> 4;
  f32x4 accP[4][2] = {}, accG[4][2] = {};
  for (int k0 = 0; k0 < K; k0 += BK) {
#pragma unroll
    for (int it = 0; it < 2; ++it) {
      int idx = it * 256 + t, r = idx >> 2, q = idx & 3, row = m0 + r;
      uint4 v = make_uint4(0u, 0u, 0u, 0u);
      if (row < Me) {
        int rg = EXPERT ? (rowmap[row] >> 1) : row;
        v = *reinterpret_cast<const uint4*>(A + (size_t)rg * lda + k0 + q * 8);
      }
      *reinterpret_cast<uint4*>(&As[r][q * 8]) = v;
    }
#pragma unroll
    for (int b = 0; b < 2; ++b) {
      const float* Bp = b ? B2 : B1;
#pragma unroll
      for (int it = 0; it < 2; ++it) {
        int idx = (it * 256 + t) * 4, kr = idx >> 6, c = idx & 63;
        float4 f = *reinterpret_cast<const float4*>(Bp + (size_t)(k0 + kr) * ldb + n0 + c);
        Bs[b][c + 0][kr] = f2bf(f.x); Bs[b][c + 1][kr] = f2bf(f.y);
        Bs[b][c + 2][kr] = f2bf(f.z); Bs[b][c + 3][kr] = f2bf(f.w);
      }
    }
    __syncthreads();
    bf16x8 af[4];
#pragma unroll
    for (int fm = 0; fm < 4; ++fm)
      af[fm] = *reinterpret_cast<const bf16x8*>(&As[wm * 64 + fm * 16 + lr][lkg * 8]);
#pragma unroll
    for (int fn = 0; fn < 2; ++fn) {
      bf16x8 bp = *reinterpret_cast<const bf16x8*>(&Bs[0][wn * 32 + fn * 16 + lr][lkg * 8]);
      bf16x8 bg = *reinterpret_cast<const bf16x8*>(&Bs[1][wn * 32 + fn * 16 + lr][lkg * 8]);
#pragma unroll
      for (int fm = 0; fm < 4; ++fm) {
        accP[fm][fn] = __builtin_amdgcn_mfma_f32_16x16x32_bf16(af[fm], bp, accP[fm][fn], 0, 0, 0);
        accG[fm][fn] = __builtin_amdgcn_mfma_f32_16x16x32_bf16(af[fm], bg, accG[fm][fn], 0, 0, 0);
      }
    }
    __syncthreads();
  }
#pragma unroll
  for (int fm = 0; fm < 4; ++fm)
#pragma unroll
    for (int fn = 0; fn < 2; ++fn)
#pragma unroll
      for (int j = 0; j < 4; ++j) {
        int grow = wm * 64 + fm * 16 + lkg * 4 + j, gcol = wn * 32 + fn * 16 + lr;
        int row = m0 + grow;
        if (row < Me) {
          float p = accP[fm][fn][j], g = accG[fm][fn][j];
          float s = p / (1.f + __expf(-p)) * g;
          int orow = EXPERT ? (offs[e] + row) : row;
          Out[(size_t)orow * ldo + n0 + gcol] = f2bf(s);
        }
      }
}

template <int EXPERT>
__global__ __launch_bounds__(256) void out_gemm_k(
    const u16* __restrict__ A, int lda,
    const int* __restrict__ cnt, const int* __restrict__ offs,
    const int* __restrict__ list, const float* __restrict__ scores,
    const float* __restrict__ Bg, int ldb, long long bstride,
    float* __restrict__ Out, const float* __restrict__ outbuf, int K) {
  __shared__ u16 As[BM][PK];
  __shared__ u16 Bs[BN][PK];
  int e = EXPERT ? blockIdx.z : 0;
  int Me = EXPERT ? cnt[e] : NTOK;
  int m0 = blockIdx.y * BM;
  if (m0 >= Me) return;
  int n0 = blockIdx.x * BN;
  const float* B = Bg + (EXPERT ? (long long)e * bstride : 0);
  int aoff = EXPERT ? offs[e] : 0;
  int t = threadIdx.x, wid = t >> 6, lane = t & 63;
  int wm = wid & 1, wn = wid >> 1, lr = lane & 15, lkg = lane >> 4;
  f32x4 acc[4][2] = {};
  for (int k0 = 0; k0 < K; k0 += BK) {
#pragma unroll
    for (int it = 0; it < 2; ++it) {
      int idx = it * 256 + t, r = idx >> 2, q = idx & 3, row = m0 + r;
      uint4 v = make_uint4(0u, 0u, 0u, 0u);
      if (row < Me)
        v = *reinterpret_cast<const uint4*>(A + (size_t)(aoff + row) * lda + k0 + q * 8);
      *reinterpret_cast<uint4*>(&As[r][q * 8]) = v;
    }
#pragma unroll
    for (int it = 0; it < 2; ++it) {
      int idx = (it * 256 + t) * 4, kr = idx >> 6, c = idx & 63;
      float4 f = *reinterpret_cast<const float4*>(B + (size_t)(k0 + kr) * ldb + n0 + c);
      Bs[c + 0][kr] = f2bf(f.x); Bs[c + 1][kr] = f2bf(f.y);
      Bs[c + 2][kr] = f2bf(f.z); Bs[c + 3][kr] = f2bf(f.w);
    }
    __syncthreads();
    bf16x8 af[4];
#pragma unroll
    for (int fm = 0; fm < 4; ++fm)
      af[fm] = *reinterpret_cast<const bf16x8*>(&As[wm * 64 + fm * 16 + lr][lkg * 8]);
#pragma unroll
    for (int fn = 0; fn < 2; ++fn) {
      bf16x8 bb = *reinterpret_cast<const bf16x8*>(&Bs[wn * 32 + fn * 16 + lr][lkg * 8]);
#pragma unroll
      for (int fm = 0; fm < 4; ++fm)
        acc[fm][fn] = __builtin_amdgcn_mfma_f32_16x16x32_bf16(af[fm], bb, acc[fm][fn], 0, 0, 0);
    }
    __syncthreads();
  }
#pragma unroll
  for (int fm = 0; fm < 4; ++fm)
#pragma unroll
    for (int fn = 0; fn < 2; ++fn)
#pragma unroll
      for (int j = 0; j < 4; ++j) {
        int grow = wm * 64 + fm * 16 + lkg * 4 + j, gcol = wn * 32 + fn * 16 + lr;
        int row = m0 + grow;
        if (row < Me) {
          float v = acc[fm][fn][j];
          int c = n0 + gcol;
          if (EXPERT) {
            int slot = list[e * NTOK + row];
            Out[(size_t)slot * H_ + c] = v * scores[slot];
          } else {
            Out[(size_t)row * H_ + c] =
                v + outbuf[(size_t)(2 * row) * H_ + c] + outbuf[(size_t)(2 * row + 1) * H_ + c];
          }
        }
      }
}

// ---------------------------------------------------------------------------
extern "C" void kernel_launch(void* const* d_in, const int* in_sizes, int n_in,
                              void* d_out, int out_size, void* d_ws, size_t ws_size,
                              hipStream_t stream) {
  const float* x   = (const float*)d_in[0];
  const float* wr  = (const float*)d_in[1];
  const float* fc1 = (const float*)d_in[2];
  const float* fc2 = (const float*)d_in[3];
  const float* gw  = (const float*)d_in[4];
  const float* uw  = (const float*)d_in[5];
  const float* dw  = (const float*)d_in[6];
  float* out = (float*)d_out;
  char* ws = (char*)d_ws;

  const size_t NEED_FAST = 131072ull + (88ull << 20);
  if (ws_size >= NEED_FAST) {
    float* scores = (float*)ws;
    int* cnt  = (int*)(ws + 16384);
    int* list = (int*)(ws + 16512);
    u16* xb   = (u16*)(ws + 131072);
    u16* act  = (u16*)(ws + 131072 + (4ll << 20));
    u16* tmp  = (u16*)(ws + 131072 + (12ll << 20));
    u16* fc1T = (u16*)(ws + 131072 + (28ll << 20));
    u16* fc2T = (u16*)(ws + 131072 + (60ll << 20));
    u16* gwT  = (u16*)(ws + 131072 + (76ll << 20));
    u16* uwT  = (u16*)(ws + 131072 + (80ll << 20));
    u16* dwT  = (u16*)(ws + 131072 + (84ll << 20));

    hipMemsetAsync(cnt, 0, 128, stream);
    hipMemsetAsync(out, 0, (size_t)NTOK * H_ * sizeof(float), stream);
    prep2_k<<<4864, 256, 0, stream>>>(x, wr, scores, cnt, list, xb,
                                      fc1, fc2, gw, uw, dw,
                                      fc1T, fc2T, gwT, uwT, dwT);
    swiglu3_k<<<1280, 256, 0, stream>>>(xb, cnt, list, fc1T, gwT, uwT, act, tmp);
    out3_k<<<1280, 256, 0, stream>>>(act, fc2T, tmp, dwT, cnt, list, scores, out);
  } else {
    float* scores = (float*)(ws);
    int*   cnt    = (int*)(ws + (16 << 10));
    int*   offs   = (int*)(ws + (16 << 10) + 128);
    int*   list   = (int*)(ws + (16 << 10) + 256);
    u16*   xb     = (u16*)(ws + (96 << 10));
    u16*   act    = (u16*)(ws + (96 << 10) + (4ll << 20));
    u16*   tmp    = (u16*)(ws + (96 << 10) + (12ll << 20));
    float* outbuf = (float*)(ws + (96 << 10) + (20ll << 20));

    hipMemsetAsync(cnt, 0, E_ * sizeof(int), stream);
    router_k<<<NTOK / 4, 256, 0, stream>>>(x, wr, scores, cnt, list);
    offs_k<<<1, 64, 0, stream>>>(cnt, offs);
    cvt_k<<<(NTOK * H_ / 4 + 255) / 256, 256, 0, stream>>>(x, xb, NTOK * H_ / 4);
    swiglu_gemm_k<1><<<dim3(I_ / BN, NTOK / BM, E_), 256, 0, stream>>>(
        xb, H_, list, cnt, offs, fc1, fc1 + I_, 2 * I_, (long long)H_ * 2 * I_, act, I_, H_);
    out_gemm_k<1><<<dim3(H_ / BN, NTOK / BM, E_), 256, 0, stream>>>(
        act, I_, cnt, offs, list, scores, fc2, H_, (long long)I_ * H_, outbuf, nullptr, I_);
    swiglu_gemm_k<0><<<dim3(ISH_ / BN, NTOK / BM, 1), 256, 0, stream>>>(
        xb, H_, nullptr, nullptr, nullptr, gw, uw, ISH_, 0, tmp, ISH_, H_);
    out_gemm_k<0><<<dim3(H_ / BN, NTOK / BM, 1), 256, 0, stream>>>(
        tmp, ISH_, nullptr, nullptr, nullptr, nullptr, dw, H_, 0, out, outbuf, ISH_);
  }
  (void)in_sizes; (void)n_in; (void)out_size;
}